// Round 14
// baseline (339.230 us; speedup 1.0000x reference)
//
#include <hip/hip_runtime.h>
#include <math.h>

// Problem constants (match reference)
#define N_ATOMS 768
#define FD 128          // feature width
#define NRBF 32
#define MAXN 64         // per-atom neighbor cap (mean ~26)
#define PPF 32          // fwd: pairs per block (4 pairs x 4 cols per thread)
#define PPBW 16         // bwd: pairs per block (2 pairs x 4 cols per thread)
#define FTILES (N_ATOMS * MAXN / PPF)     // 1536
#define BTILES (N_ATOMS * MAXN / PPBW)    // 3072
#define AST 132         // padded LDS stride for [*][128] tiles (16B-aligned)
#define RST 36          // padded LDS stride for [*][32] rbf tiles

constexpr float  CUT2   = 25.0f;
constexpr float  GAMMA_ = 40.96f;            // 1/(5/32)^2
constexpr float  CSTEP  = 5.0f / 31.0f;      // linspace(0,5,32) step
constexpr double KB_D   = 8.617330337217213e-05;
constexpr double KT_D   = 300.0 * KB_D;
constexpr float  KT_F   = (float)KT_D;
constexpr float  TARGET_KE = (float)(0.5 * 2304.0 * KT_D);
constexpr float  Q0_F   = (float)(2.0 * 2304.0 * KT_D * 400.0);  // Q[0]
constexpr float  QI_F   = (float)(2.0 * KT_D * 400.0);           // Q[1..3]

#define DVDT_OFF 0
#define V_OFF    (3 * N_ATOMS)
#define PETA_OFF (6 * N_ATOMS)

// Register discipline (R3/R5/R6/R7/R9/R11): ANY __launch_bounds__ min-wave
// hint on the GEMM kernels -> compiler squeezes VGPRs -> scratch spills ->
// symmetric 100s-of-MB FETCH/WRITE, dur ~ spill/2.5TB/s. NO HINTS.
// Tile economics (R12/R13): fwd wants PPF=32 (W2 row stream amortized over
// more pairs); bwd (post-diet, lighter inner loop) wants PPBW=16 (grid fill).

// ---------------------------------------------------------------- prep
__global__ __launch_bounds__(256) void prep_kernel(
    const float* __restrict__ q, const int* __restrict__ z,
    const float* __restrict__ embed, const float* __restrict__ W2,
    const float* __restrict__ W3,
    float* __restrict__ h, float* __restrict__ W2T, float* __restrict__ W3T,
    int* __restrict__ pair_i, int* __restrict__ pair_j,
    float* __restrict__ pair_d, float* __restrict__ pair_dx,
    float* __restrict__ pair_dy, float* __restrict__ pair_dz,
    int* __restrict__ npairs_ctr,
    float* __restrict__ m, float* __restrict__ f_acc)
{
    __shared__ int   nj[MAXN];
    __shared__ float nd[MAXN], ndx[MAXN], ndy[MAXN], ndz[MAXN];
    __shared__ int cnt_s, base_s;
    int i = blockIdx.x, t = threadIdx.x;
    if (t == 0) cnt_s = 0;
    __syncthreads();
    float qx = q[i*3], qy = q[i*3+1], qz = q[i*3+2];
    for (int j = t; j < N_ATOMS; j += 256) {
        if (j == i) continue;
        float dx = qx - q[j*3], dy = qy - q[j*3+1], dz = qz - q[j*3+2];
        float d2 = dx*dx + dy*dy + dz*dz;
        if (d2 < CUT2) {
            int p = atomicAdd(&cnt_s, 1);
            if (p < MAXN) { nj[p] = j; nd[p] = sqrtf(d2);
                            ndx[p] = dx; ndy[p] = dy; ndz[p] = dz; }
        }
    }
    int g = i * 256 + t;                         // 196608 global ids
    if (g < N_ATOMS * FD) { h[g] = embed[z[g >> 7] * FD + (g & 127)]; m[g] = 0.f; }
    int g2 = g - N_ATOMS * FD;
    if (g2 >= 0 && g2 < FD * FD) {
        int r = g2 >> 7, c = g2 & 127;
        W2T[c * FD + r] = W2[g2];
        W3T[c * FD + r] = W3[g2];
    }
    if (g < 3 * N_ATOMS) f_acc[g] = 0.f;
    __syncthreads();
    if (t == 0) base_s = atomicAdd(npairs_ctr, min(cnt_s, MAXN));
    __syncthreads();
    int cnt = min(cnt_s, MAXN), base = base_s;
    if (t < cnt) {
        pair_i[base+t] = i;      pair_j[base+t] = nj[t];
        pair_d[base+t] = nd[t];  pair_dx[base+t] = ndx[t];
        pair_dy[base+t] = ndy[t]; pair_dz[base+t] = ndz[t];
    }
}

// ---------------------------------------------------------------- fwd (PPF=32)
__global__ __launch_bounds__(256) void fwd_kernel(
    const float* __restrict__ W1, const float* __restrict__ b1,
    const float* __restrict__ W2, const float* __restrict__ b2,
    const float* __restrict__ h,
    const int* __restrict__ pair_i, const int* __restrict__ pair_j,
    const float* __restrict__ pair_d, const int* __restrict__ npairs_ctr,
    float* __restrict__ m)
{
    __shared__ float rbf_s[PPF * RST];   //  4608 B
    __shared__ float a1_s[PPF * AST];    // 16896 B
    __shared__ int   pis[PPF], pjs[PPF]; //   256 B
    int t = threadIdx.x;
    int base = blockIdx.x * PPF;
    int np = npairs_ctr[0];
    if (base >= np) return;

    if (t < PPF) {
        int p = base + t; bool ok = p < np;
        pis[t] = ok ? pair_i[p] : 0;
        pjs[t] = ok ? pair_j[p] : 0;
    }
    for (int idx = t; idx < PPF * NRBF; idx += 256) {
        int p = idx >> 5, k = idx & 31;
        int gp = base + p;
        float d = (gp < np) ? pair_d[gp] : 1.0f;
        float u = d - CSTEP * (float)k;
        rbf_s[p * RST + k] = __expf(-GAMMA_ * u * u);
    }
    __syncthreads();

    // GEMM-1: a1[p][c] = relu(b1[c] + rbf[p]@W1[:,c]); thread = (c, 16-pair half)
    {
        int c = t & 127, ph = t >> 7;
        float w1c[NRBF];
#pragma unroll
        for (int k = 0; k < NRBF; k++) w1c[k] = W1[k * FD + c];
        float b1c = b1[c];
        for (int p = ph * 16; p < ph * 16 + 16; p++) {
            float u = b1c;
#pragma unroll
            for (int k4 = 0; k4 < NRBF / 4; k4++) {
                float4 r = *(const float4*)(rbf_s + p * RST + k4 * 4);
                u += r.x*w1c[k4*4] + r.y*w1c[k4*4+1] + r.z*w1c[k4*4+2] + r.w*w1c[k4*4+3];
            }
            a1_s[p * AST + c] = fmaxf(u, 0.f);
        }
    }
    __syncthreads();

    // GEMM-2: thread = subtile st (4 pairs) x col-granule cg (4 cols)
    int st = t >> 5, cg = t & 31, c4 = 4 * cg;
    float acc[4][4];
#pragma unroll
    for (int e = 0; e < 4; e++) { acc[e][0]=0; acc[e][1]=0; acc[e][2]=0; acc[e][3]=0; }
    for (int k = 0; k < FD; k += 4) {
        float4 w0 = *(const float4*)(W2 + (k+0) * FD + c4);
        float4 w1v= *(const float4*)(W2 + (k+1) * FD + c4);
        float4 w2v= *(const float4*)(W2 + (k+2) * FD + c4);
        float4 w3v= *(const float4*)(W2 + (k+3) * FD + c4);
#pragma unroll
        for (int e = 0; e < 4; e++) {
            float4 a = *(const float4*)(a1_s + (st*4+e) * AST + k);
            acc[e][0] += a.x*w0.x + a.y*w1v.x + a.z*w2v.x + a.w*w3v.x;
            acc[e][1] += a.x*w0.y + a.y*w1v.y + a.z*w2v.y + a.w*w3v.y;
            acc[e][2] += a.x*w0.z + a.y*w1v.z + a.z*w2v.z + a.w*w3v.z;
            acc[e][3] += a.x*w0.w + a.y*w1v.w + a.z*w2v.w + a.w*w3v.w;
        }
    }
    float4 b2v = *(const float4*)(b2 + c4);
    float r0 = 0, r1 = 0, r2 = 0, r3 = 0;
    int cur_i = pis[st * 4];
#pragma unroll
    for (int e = 0; e < 4; e++) {
        int lp = st * 4 + e, gp = base + lp;
        int ip = pis[lp];
        if (ip != cur_i) {
            atomicAdd(m + cur_i*FD + c4 + 0, r0);
            atomicAdd(m + cur_i*FD + c4 + 1, r1);
            atomicAdd(m + cur_i*FD + c4 + 2, r2);
            atomicAdd(m + cur_i*FD + c4 + 3, r3);
            r0 = r1 = r2 = r3 = 0; cur_i = ip;
        }
        if (gp < np) {
            float4 hj = *(const float4*)(h + pjs[lp] * FD + c4);
            r0 += (acc[e][0] + b2v.x) * hj.x;
            r1 += (acc[e][1] + b2v.y) * hj.y;
            r2 += (acc[e][2] + b2v.z) * hj.z;
            r3 += (acc[e][3] + b2v.w) * hj.w;
        }
    }
    atomicAdd(m + cur_i*FD + c4 + 0, r0);
    atomicAdd(m + cur_i*FD + c4 + 1, r1);
    atomicAdd(m + cur_i*FD + c4 + 2, r2);
    atomicAdd(m + cur_i*FD + c4 + 3, r3);
}

// ---------------------------------------------------------------- mbar (per atom)
__global__ __launch_bounds__(128) void mbar_kernel(
    const float* __restrict__ m, const float* __restrict__ W3,
    const float* __restrict__ W3T, const float* __restrict__ w_out,
    float* __restrict__ mbar)
{
    __shared__ float ms[FD];
    __shared__ float gb[FD];
    int i = blockIdx.x, t = threadIdx.x;
    ms[t] = m[i * FD + t];
    __syncthreads();
    float g = 0.f;
#pragma unroll 8
    for (int f = 0; f < FD; f++) g += ms[f] * W3[f * FD + t];
    gb[t] = (g > 0.f) ? w_out[t] : 0.f;
    __syncthreads();
    float mb = 0.f;
#pragma unroll 8
    for (int c = 0; c < FD; c++) mb += gb[c] * W3T[c * FD + t];
    mbar[i * FD + t] = mb;
}

// ---------------------------------------------------------------- bwd (PPBW=16)
// R12 register-diet structure + fused finalize (completion counter; last
// block computes dvdt/v/KE/dpeta with coherent atomic reads of f_acc).
__global__ __launch_bounds__(256) void bwd_kernel(
    const float* __restrict__ W1, const float* __restrict__ b1,
    const float* __restrict__ W2T, const float* __restrict__ h,
    const float* __restrict__ mbar,
    const int* __restrict__ pair_i, const int* __restrict__ pair_j,
    const float* __restrict__ pair_d, const float* __restrict__ pair_dx,
    const float* __restrict__ pair_dy, const float* __restrict__ pair_dz,
    const int* __restrict__ npairs_ctr, float* __restrict__ f_acc,
    int* __restrict__ done_ctr,
    const float* __restrict__ v, const float* __restrict__ mass,
    const float* __restrict__ p_eta, float* __restrict__ out)
{
    __shared__ float rbf_s[PPBW * RST];    //  2304 B
    __shared__ float crbf_s[PPBW * RST];   //  2304 B
    __shared__ float ts[PPBW * AST];       //  8448 B
    __shared__ float gef[PPBW * AST];      //  8448 B
    __shared__ int   pis[PPBW], pjs[PPBW];
    __shared__ float redk[256];
    __shared__ int lastflag;
    int t = threadIdx.x;
    int base = blockIdx.x * PPBW;
    int np = npairs_ctr[0];

    if (base < np) {
        if (t < PPBW) {
            int p = base + t; bool ok = p < np;
            pis[t] = ok ? pair_i[p] : 0;
            pjs[t] = ok ? pair_j[p] : 0;
        }
        for (int idx = t; idx < PPBW * NRBF; idx += 256) {
            int p = idx >> 5, k = idx & 31;
            int gp = base + p;
            float d = (gp < np) ? pair_d[gp] : 1.0f;
            float u = d - CSTEP * (float)k;
            float r = __expf(-GAMMA_ * u * u);
            rbf_s[p * RST + k]  = r;
            crbf_s[p * RST + k] = -2.f * GAMMA_ * u * r;
        }
        __syncthreads();
        for (int idx = t; idx < PPBW * 32; idx += 256) {
            int p = idx >> 5, c4g = (idx & 31) * 4;
            float4 mb4 = *(const float4*)(mbar + pis[p] * FD + c4g);
            float4 hj4 = *(const float4*)(h + pjs[p] * FD + c4g);
            float4 tv; tv.x = mb4.x*hj4.x; tv.y = mb4.y*hj4.y;
            tv.z = mb4.z*hj4.z; tv.w = mb4.w*hj4.w;
            *(float4*)(ts + p * AST + c4g) = tv;
        }
        // gef phase: thread = (c, 8-pair half); w1c regs die here
        {
            int c = t & 127, ph = t >> 7;
            float w1c[NRBF];
#pragma unroll
            for (int k = 0; k < NRBF; k++) w1c[k] = W1[k * FD + c];
            float b1c = b1[c];
            for (int p = ph * 8; p < ph * 8 + 8; p++) {
                float u1 = b1c, ef = 0.f;
#pragma unroll
                for (int k4 = 0; k4 < NRBF / 4; k4++) {
                    float4 r = *(const float4*)(rbf_s  + p * RST + k4 * 4);
                    float4 cd= *(const float4*)(crbf_s + p * RST + k4 * 4);
                    u1 += r.x*w1c[k4*4] + r.y*w1c[k4*4+1] + r.z*w1c[k4*4+2] + r.w*w1c[k4*4+3];
                    ef += cd.x*w1c[k4*4] + cd.y*w1c[k4*4+1] + cd.z*w1c[k4*4+2] + cd.w*w1c[k4*4+3];
                }
                gef[p * AST + c] = (u1 > 0.f) ? ef : 0.f;
            }
        }
        __syncthreads();

        // GEMM: du1[p][c4..] = ts[p] @ W2T[:,c4..]; fold gef immediately.
        int st = t >> 5, cg = t & 31, c4 = 4 * cg;
        float acc[2][4];
#pragma unroll
        for (int e = 0; e < 2; e++) { acc[e][0]=0; acc[e][1]=0; acc[e][2]=0; acc[e][3]=0; }
        for (int k = 0; k < FD; k += 4) {
            float4 w0 = *(const float4*)(W2T + (k+0) * FD + c4);
            float4 w1v= *(const float4*)(W2T + (k+1) * FD + c4);
            float4 w2v= *(const float4*)(W2T + (k+2) * FD + c4);
            float4 w3v= *(const float4*)(W2T + (k+3) * FD + c4);
#pragma unroll
            for (int e = 0; e < 2; e++) {
                float4 a = *(const float4*)(ts + (st*2+e) * AST + k);
                acc[e][0] += a.x*w0.x + a.y*w1v.x + a.z*w2v.x + a.w*w3v.x;
                acc[e][1] += a.x*w0.y + a.y*w1v.y + a.z*w2v.y + a.w*w3v.y;
                acc[e][2] += a.x*w0.z + a.y*w1v.z + a.z*w2v.z + a.w*w3v.z;
                acc[e][3] += a.x*w0.w + a.y*w1v.w + a.z*w2v.w + a.w*w3v.w;
            }
        }
#pragma unroll
        for (int e = 0; e < 2; e++) {
            float4 g4 = *(const float4*)(gef + (st*2+e) * AST + c4);
            float s = acc[e][0]*g4.x + acc[e][1]*g4.y + acc[e][2]*g4.z + acc[e][3]*g4.w;
            s += __shfl_xor(s, 1, 64);
            s += __shfl_xor(s, 2, 64);
            s += __shfl_xor(s, 4, 64);
            s += __shfl_xor(s, 8, 64);
            s += __shfl_xor(s, 16, 64);
            int gp = base + st * 2 + e;
            if (cg == e && gp < np) {
                int ii = pis[st * 2 + e], jj = pjs[st * 2 + e];
                float coef = s / pair_d[gp];
                float fx = coef * pair_dx[gp];
                float fy = coef * pair_dy[gp];
                float fz = coef * pair_dz[gp];
                atomicAdd(f_acc + ii*3 + 0, -fx);
                atomicAdd(f_acc + ii*3 + 1, -fy);
                atomicAdd(f_acc + ii*3 + 2, -fz);
                atomicAdd(f_acc + jj*3 + 0, fx);
                atomicAdd(f_acc + jj*3 + 1, fy);
                atomicAdd(f_acc + jj*3 + 2, fz);
            }
        }
    }
    // ---- completion counter: ALL blocks arrive; last block finalizes ----
    __threadfence();
    if (t == 0) lastflag = (atomicAdd(done_ctr, 1) == (int)gridDim.x - 1);
    __syncthreads();
    if (lastflag) {
        float ke = 0.f;
        float c = p_eta[0] / Q0_F;
        for (int idx = t; idx < 3 * N_ATOMS; idx += 256) {
            int a = idx / 3;
            float fa = atomicAdd(f_acc + idx, 0.f);   // coherent cross-XCD read
            float vv = v[idx], mi = mass[a];
            out[DVDT_OFF + idx] = (fa - c * vv * mi) / mi;
            out[V_OFF + idx] = vv;
            ke += 0.5f * mi * vv * vv;
        }
        redk[t] = ke;
        __syncthreads();
        for (int s = 128; s > 0; s >>= 1) {
            if (t < s) redk[t] += redk[t + s];
            __syncthreads();
        }
        if (t == 0) {
            float k0 = redk[0];
            float e0 = p_eta[0], e1 = p_eta[1], e2 = p_eta[2], e3 = p_eta[3];
            out[PETA_OFF + 0] = 2.f * (k0 - TARGET_KE) - e0 * e1 / QI_F;
            out[PETA_OFF + 1] = e0 * e0 / Q0_F - KT_F - e1 * e2 / QI_F;
            out[PETA_OFF + 2] = e1 * e1 / QI_F - KT_F - e2 * e3 / QI_F;
            out[PETA_OFF + 3] = e2 * e2 / QI_F - KT_F;
        }
    }
}

// ---------------------------------------------------------------- launch
extern "C" void kernel_launch(void* const* d_in, const int* in_sizes, int n_in,
                              void* d_out, int out_size, void* d_ws, size_t ws_size,
                              hipStream_t stream)
{
    const float* v     = (const float*)d_in[0];
    const float* q     = (const float*)d_in[1];
    const float* p_eta = (const float*)d_in[2];
    const float* mass  = (const float*)d_in[3];
    const float* embed = (const float*)d_in[4];
    const float* W1    = (const float*)d_in[5];
    const float* b1    = (const float*)d_in[6];
    const float* W2    = (const float*)d_in[7];
    const float* b2    = (const float*)d_in[8];
    const float* W3    = (const float*)d_in[9];
    const float* wout  = (const float*)d_in[10];
    const int*   z     = (const int*)d_in[11];
    float* out = (float*)d_out;

    float* h     = (float*)d_ws;
    float* W2T   = h + N_ATOMS * FD;
    float* W3T   = W2T + FD * FD;
    float* m     = W3T + FD * FD;
    float* mbar  = m + N_ATOMS * FD;
    float* f_acc = mbar + N_ATOMS * FD;
    float* pair_d  = f_acc + 3 * N_ATOMS;
    float* pair_dx = pair_d + N_ATOMS * MAXN;
    float* pair_dy = pair_dx + N_ATOMS * MAXN;
    float* pair_dz = pair_dy + N_ATOMS * MAXN;
    int* pair_i = (int*)(pair_dz + N_ATOMS * MAXN);
    int* pair_j = pair_i + N_ATOMS * MAXN;
    int* npairs_ctr = pair_j + N_ATOMS * MAXN;   // [0]=pair count, [1]=done ctr
    int* done_ctr   = npairs_ctr + 1;

    hipMemsetAsync(npairs_ctr, 0, 2 * sizeof(int), stream);

    prep_kernel<<<N_ATOMS, 256, 0, stream>>>(q, z, embed, W2, W3, h, W2T, W3T,
                                             pair_i, pair_j, pair_d,
                                             pair_dx, pair_dy, pair_dz,
                                             npairs_ctr, m, f_acc);
    fwd_kernel<<<FTILES, 256, 0, stream>>>(W1, b1, W2, b2, h, pair_i,
                                           pair_j, pair_d, npairs_ctr, m);
    mbar_kernel<<<N_ATOMS, 128, 0, stream>>>(m, W3, W3T, wout, mbar);
    bwd_kernel<<<BTILES, 256, 0, stream>>>(W1, b1, W2T, h, mbar, pair_i,
                                           pair_j, pair_d, pair_dx, pair_dy,
                                           pair_dz, npairs_ctr, f_acc,
                                           done_ctr, v, mass, p_eta, out);
}

// Round 15
// 170.163 us; speedup vs baseline: 1.9936x; 1.9936x over previous
//
#include <hip/hip_runtime.h>
#include <math.h>

// Problem constants (match reference)
#define N_ATOMS 768
#define FD 128          // feature width
#define NRBF 32
#define MAXN 64         // per-atom neighbor cap (mean ~26)
#define PPF 32          // fwd: pairs per block (4 pairs x 4 cols per thread)
#define PPBW 16         // bwd: pairs per block (2 pairs x 4 cols per thread)
#define FTILES (N_ATOMS * MAXN / PPF)     // 1536
#define BTILES (N_ATOMS * MAXN / PPBW)    // 3072
#define AST 132         // padded LDS stride for [*][128] tiles (16B-aligned)
#define RST 36          // padded LDS stride for [*][32] rbf tiles

constexpr float  CUT2   = 25.0f;
constexpr float  GAMMA_ = 40.96f;            // 1/(5/32)^2
constexpr float  CSTEP  = 5.0f / 31.0f;      // linspace(0,5,32) step
constexpr double KB_D   = 8.617330337217213e-05;
constexpr double KT_D   = 300.0 * KB_D;
constexpr float  KT_F   = (float)KT_D;
constexpr float  TARGET_KE = (float)(0.5 * 2304.0 * KT_D);
constexpr float  Q0_F   = (float)(2.0 * 2304.0 * KT_D * 400.0);  // Q[0]
constexpr float  QI_F   = (float)(2.0 * KT_D * 400.0);           // Q[1..3]

#define DVDT_OFF 0
#define V_OFF    (3 * N_ATOMS)
#define PETA_OFF (6 * N_ATOMS)

// Hard-won rules (14 rounds of counters):
// 1. NO __launch_bounds__ min-wave hints on GEMM kernels — compiler squeezes
//    VGPRs below demand -> scratch spills -> 100s-of-MB symmetric FETCH/WRITE,
//    dur ~ spill/2.5 TB/s (R3/R5/R6/R7/R9/R11).
// 2. Reduce register demand STRUCTURALLY (R12 gef-phase diet: 220->80 VGPR).
// 3. Tile economics differ per kernel: fwd wants PPF=32 (W2 stream amortized),
//    bwd wants PPBW=16 (grid fill; lighter inner loop) (R12/R13).
// 4. NEVER put __threadfence / completion counters on the hot grid — device
//    fence ~ L2 flush per block: R14 bwd 44.6 -> 225 us (also explains R8).

// ---------------------------------------------------------------- prep
__global__ __launch_bounds__(256) void prep_kernel(
    const float* __restrict__ q, const int* __restrict__ z,
    const float* __restrict__ embed, const float* __restrict__ W2,
    const float* __restrict__ W3,
    float* __restrict__ h, float* __restrict__ W2T, float* __restrict__ W3T,
    int* __restrict__ pair_i, int* __restrict__ pair_j,
    float* __restrict__ pair_d, float* __restrict__ pair_dx,
    float* __restrict__ pair_dy, float* __restrict__ pair_dz,
    int* __restrict__ npairs_ctr,
    float* __restrict__ m, float* __restrict__ f_acc)
{
    __shared__ int   nj[MAXN];
    __shared__ float nd[MAXN], ndx[MAXN], ndy[MAXN], ndz[MAXN];
    __shared__ int cnt_s, base_s;
    int i = blockIdx.x, t = threadIdx.x;
    if (t == 0) cnt_s = 0;
    __syncthreads();
    float qx = q[i*3], qy = q[i*3+1], qz = q[i*3+2];
    for (int j = t; j < N_ATOMS; j += 256) {
        if (j == i) continue;
        float dx = qx - q[j*3], dy = qy - q[j*3+1], dz = qz - q[j*3+2];
        float d2 = dx*dx + dy*dy + dz*dz;
        if (d2 < CUT2) {
            int p = atomicAdd(&cnt_s, 1);
            if (p < MAXN) { nj[p] = j; nd[p] = sqrtf(d2);
                            ndx[p] = dx; ndy[p] = dy; ndz[p] = dz; }
        }
    }
    int g = i * 256 + t;                         // 196608 global ids
    if (g < N_ATOMS * FD) { h[g] = embed[z[g >> 7] * FD + (g & 127)]; m[g] = 0.f; }
    int g2 = g - N_ATOMS * FD;
    if (g2 >= 0 && g2 < FD * FD) {
        int r = g2 >> 7, c = g2 & 127;
        W2T[c * FD + r] = W2[g2];
        W3T[c * FD + r] = W3[g2];
    }
    if (g < 3 * N_ATOMS) f_acc[g] = 0.f;
    __syncthreads();
    if (t == 0) base_s = atomicAdd(npairs_ctr, min(cnt_s, MAXN));
    __syncthreads();
    int cnt = min(cnt_s, MAXN), base = base_s;
    if (t < cnt) {
        pair_i[base+t] = i;      pair_j[base+t] = nj[t];
        pair_d[base+t] = nd[t];  pair_dx[base+t] = ndx[t];
        pair_dy[base+t] = ndy[t]; pair_dz[base+t] = ndz[t];
    }
}

// ---------------------------------------------------------------- fwd (PPF=32)
__global__ __launch_bounds__(256) void fwd_kernel(
    const float* __restrict__ W1, const float* __restrict__ b1,
    const float* __restrict__ W2, const float* __restrict__ b2,
    const float* __restrict__ h,
    const int* __restrict__ pair_i, const int* __restrict__ pair_j,
    const float* __restrict__ pair_d, const int* __restrict__ npairs_ctr,
    float* __restrict__ m)
{
    __shared__ float rbf_s[PPF * RST];   //  4608 B
    __shared__ float a1_s[PPF * AST];    // 16896 B
    __shared__ int   pis[PPF], pjs[PPF]; //   256 B
    int t = threadIdx.x;
    int base = blockIdx.x * PPF;
    int np = npairs_ctr[0];
    if (base >= np) return;

    if (t < PPF) {
        int p = base + t; bool ok = p < np;
        pis[t] = ok ? pair_i[p] : 0;
        pjs[t] = ok ? pair_j[p] : 0;
    }
    for (int idx = t; idx < PPF * NRBF; idx += 256) {
        int p = idx >> 5, k = idx & 31;
        int gp = base + p;
        float d = (gp < np) ? pair_d[gp] : 1.0f;
        float u = d - CSTEP * (float)k;
        rbf_s[p * RST + k] = __expf(-GAMMA_ * u * u);
    }
    __syncthreads();

    // GEMM-1: a1[p][c] = relu(b1[c] + rbf[p]@W1[:,c]); thread = (c, 16-pair half)
    {
        int c = t & 127, ph = t >> 7;
        float w1c[NRBF];
#pragma unroll
        for (int k = 0; k < NRBF; k++) w1c[k] = W1[k * FD + c];
        float b1c = b1[c];
        for (int p = ph * 16; p < ph * 16 + 16; p++) {
            float u = b1c;
#pragma unroll
            for (int k4 = 0; k4 < NRBF / 4; k4++) {
                float4 r = *(const float4*)(rbf_s + p * RST + k4 * 4);
                u += r.x*w1c[k4*4] + r.y*w1c[k4*4+1] + r.z*w1c[k4*4+2] + r.w*w1c[k4*4+3];
            }
            a1_s[p * AST + c] = fmaxf(u, 0.f);
        }
    }
    __syncthreads();

    // GEMM-2: thread = subtile st (4 pairs) x col-granule cg (4 cols)
    int st = t >> 5, cg = t & 31, c4 = 4 * cg;
    float acc[4][4];
#pragma unroll
    for (int e = 0; e < 4; e++) { acc[e][0]=0; acc[e][1]=0; acc[e][2]=0; acc[e][3]=0; }
    for (int k = 0; k < FD; k += 4) {
        float4 w0 = *(const float4*)(W2 + (k+0) * FD + c4);
        float4 w1v= *(const float4*)(W2 + (k+1) * FD + c4);
        float4 w2v= *(const float4*)(W2 + (k+2) * FD + c4);
        float4 w3v= *(const float4*)(W2 + (k+3) * FD + c4);
#pragma unroll
        for (int e = 0; e < 4; e++) {
            float4 a = *(const float4*)(a1_s + (st*4+e) * AST + k);
            acc[e][0] += a.x*w0.x + a.y*w1v.x + a.z*w2v.x + a.w*w3v.x;
            acc[e][1] += a.x*w0.y + a.y*w1v.y + a.z*w2v.y + a.w*w3v.y;
            acc[e][2] += a.x*w0.z + a.y*w1v.z + a.z*w2v.z + a.w*w3v.z;
            acc[e][3] += a.x*w0.w + a.y*w1v.w + a.z*w2v.w + a.w*w3v.w;
        }
    }
    float4 b2v = *(const float4*)(b2 + c4);
    float r0 = 0, r1 = 0, r2 = 0, r3 = 0;
    int cur_i = pis[st * 4];
#pragma unroll
    for (int e = 0; e < 4; e++) {
        int lp = st * 4 + e, gp = base + lp;
        int ip = pis[lp];
        if (ip != cur_i) {
            atomicAdd(m + cur_i*FD + c4 + 0, r0);
            atomicAdd(m + cur_i*FD + c4 + 1, r1);
            atomicAdd(m + cur_i*FD + c4 + 2, r2);
            atomicAdd(m + cur_i*FD + c4 + 3, r3);
            r0 = r1 = r2 = r3 = 0; cur_i = ip;
        }
        if (gp < np) {
            float4 hj = *(const float4*)(h + pjs[lp] * FD + c4);
            r0 += (acc[e][0] + b2v.x) * hj.x;
            r1 += (acc[e][1] + b2v.y) * hj.y;
            r2 += (acc[e][2] + b2v.z) * hj.z;
            r3 += (acc[e][3] + b2v.w) * hj.w;
        }
    }
    atomicAdd(m + cur_i*FD + c4 + 0, r0);
    atomicAdd(m + cur_i*FD + c4 + 1, r1);
    atomicAdd(m + cur_i*FD + c4 + 2, r2);
    atomicAdd(m + cur_i*FD + c4 + 3, r3);
}

// ---------------------------------------------------------------- mbar (per atom)
__global__ __launch_bounds__(128) void mbar_kernel(
    const float* __restrict__ m, const float* __restrict__ W3,
    const float* __restrict__ W3T, const float* __restrict__ w_out,
    float* __restrict__ mbar)
{
    __shared__ float ms[FD];
    __shared__ float gb[FD];
    int i = blockIdx.x, t = threadIdx.x;
    ms[t] = m[i * FD + t];
    __syncthreads();
    float g = 0.f;
#pragma unroll 8
    for (int f = 0; f < FD; f++) g += ms[f] * W3[f * FD + t];
    gb[t] = (g > 0.f) ? w_out[t] : 0.f;
    __syncthreads();
    float mb = 0.f;
#pragma unroll 8
    for (int c = 0; c < FD; c++) mb += gb[c] * W3T[c * FD + t];
    mbar[i * FD + t] = mb;
}

// ---------------------------------------------------------------- bwd (PPBW=16)
// R12 register-diet structure (gef phase in LDS), R13 tile size. No fences.
__global__ __launch_bounds__(256) void bwd_kernel(
    const float* __restrict__ W1, const float* __restrict__ b1,
    const float* __restrict__ W2T, const float* __restrict__ h,
    const float* __restrict__ mbar,
    const int* __restrict__ pair_i, const int* __restrict__ pair_j,
    const float* __restrict__ pair_d, const float* __restrict__ pair_dx,
    const float* __restrict__ pair_dy, const float* __restrict__ pair_dz,
    const int* __restrict__ npairs_ctr, float* __restrict__ f_acc)
{
    __shared__ float rbf_s[PPBW * RST];    //  2304 B
    __shared__ float crbf_s[PPBW * RST];   //  2304 B
    __shared__ float ts[PPBW * AST];       //  8448 B
    __shared__ float gef[PPBW * AST];      //  8448 B
    __shared__ int   pis[PPBW], pjs[PPBW];
    int t = threadIdx.x;
    int base = blockIdx.x * PPBW;
    int np = npairs_ctr[0];
    if (base >= np) return;

    if (t < PPBW) {
        int p = base + t; bool ok = p < np;
        pis[t] = ok ? pair_i[p] : 0;
        pjs[t] = ok ? pair_j[p] : 0;
    }
    for (int idx = t; idx < PPBW * NRBF; idx += 256) {
        int p = idx >> 5, k = idx & 31;
        int gp = base + p;
        float d = (gp < np) ? pair_d[gp] : 1.0f;
        float u = d - CSTEP * (float)k;
        float r = __expf(-GAMMA_ * u * u);
        rbf_s[p * RST + k]  = r;
        crbf_s[p * RST + k] = -2.f * GAMMA_ * u * r;
    }
    __syncthreads();                       // pis/pjs + rbf/crbf ready

    // ts tile: ts[p][c] = mbar_i[c] * h[j_p][c]
    for (int idx = t; idx < PPBW * 32; idx += 256) {
        int p = idx >> 5, c4g = (idx & 31) * 4;
        float4 mb4 = *(const float4*)(mbar + pis[p] * FD + c4g);
        float4 hj4 = *(const float4*)(h + pjs[p] * FD + c4g);
        float4 tv; tv.x = mb4.x*hj4.x; tv.y = mb4.y*hj4.y;
        tv.z = mb4.z*hj4.z; tv.w = mb4.w*hj4.w;
        *(float4*)(ts + p * AST + c4g) = tv;
    }
    // gef phase: thread = (c, 8-pair half); w1c regs die at phase end
    {
        int c = t & 127, ph = t >> 7;
        float w1c[NRBF];
#pragma unroll
        for (int k = 0; k < NRBF; k++) w1c[k] = W1[k * FD + c];
        float b1c = b1[c];
        for (int p = ph * 8; p < ph * 8 + 8; p++) {
            float u1 = b1c, ef = 0.f;
#pragma unroll
            for (int k4 = 0; k4 < NRBF / 4; k4++) {
                float4 r = *(const float4*)(rbf_s  + p * RST + k4 * 4);
                float4 cd= *(const float4*)(crbf_s + p * RST + k4 * 4);
                u1 += r.x*w1c[k4*4] + r.y*w1c[k4*4+1] + r.z*w1c[k4*4+2] + r.w*w1c[k4*4+3];
                ef += cd.x*w1c[k4*4] + cd.y*w1c[k4*4+1] + cd.z*w1c[k4*4+2] + cd.w*w1c[k4*4+3];
            }
            gef[p * AST + c] = (u1 > 0.f) ? ef : 0.f;
        }
    }
    __syncthreads();

    // GEMM: du1[p][c4..] = ts[p] @ W2T[:,c4..]; fold gef immediately.
    int st = t >> 5, cg = t & 31, c4 = 4 * cg;
    float acc[2][4];
#pragma unroll
    for (int e = 0; e < 2; e++) { acc[e][0]=0; acc[e][1]=0; acc[e][2]=0; acc[e][3]=0; }
    for (int k = 0; k < FD; k += 4) {
        float4 w0 = *(const float4*)(W2T + (k+0) * FD + c4);
        float4 w1v= *(const float4*)(W2T + (k+1) * FD + c4);
        float4 w2v= *(const float4*)(W2T + (k+2) * FD + c4);
        float4 w3v= *(const float4*)(W2T + (k+3) * FD + c4);
#pragma unroll
        for (int e = 0; e < 2; e++) {
            float4 a = *(const float4*)(ts + (st*2+e) * AST + k);
            acc[e][0] += a.x*w0.x + a.y*w1v.x + a.z*w2v.x + a.w*w3v.x;
            acc[e][1] += a.x*w0.y + a.y*w1v.y + a.z*w2v.y + a.w*w3v.y;
            acc[e][2] += a.x*w0.z + a.y*w1v.z + a.z*w2v.z + a.w*w3v.z;
            acc[e][3] += a.x*w0.w + a.y*w1v.w + a.z*w2v.w + a.w*w3v.w;
        }
    }
#pragma unroll
    for (int e = 0; e < 2; e++) {
        float4 g4 = *(const float4*)(gef + (st*2+e) * AST + c4);
        float s = acc[e][0]*g4.x + acc[e][1]*g4.y + acc[e][2]*g4.z + acc[e][3]*g4.w;
        s += __shfl_xor(s, 1, 64);
        s += __shfl_xor(s, 2, 64);
        s += __shfl_xor(s, 4, 64);
        s += __shfl_xor(s, 8, 64);
        s += __shfl_xor(s, 16, 64);
        int gp = base + st * 2 + e;
        if (cg == e && gp < np) {
            int ii = pis[st * 2 + e], jj = pjs[st * 2 + e];
            float coef = s / pair_d[gp];
            float fx = coef * pair_dx[gp];
            float fy = coef * pair_dy[gp];
            float fz = coef * pair_dz[gp];
            atomicAdd(f_acc + ii*3 + 0, -fx);
            atomicAdd(f_acc + ii*3 + 1, -fy);
            atomicAdd(f_acc + ii*3 + 2, -fz);
            atomicAdd(f_acc + jj*3 + 0, fx);
            atomicAdd(f_acc + jj*3 + 1, fy);
            atomicAdd(f_acc + jj*3 + 2, fz);
        }
    }
}

// ---------------------------------------------------------------- finalize
__global__ __launch_bounds__(256) void fin_kernel(
    const float* __restrict__ v, const float* __restrict__ mass,
    const float* __restrict__ p_eta, const float* __restrict__ f_acc,
    float* __restrict__ out)
{
    __shared__ float red[256];
    int t = threadIdx.x;
    float ke = 0.f;
    float c = p_eta[0] / Q0_F;
    for (int idx = t; idx < 3 * N_ATOMS; idx += 256) {
        int a = idx / 3;
        float vv = v[idx], mi = mass[a];
        out[DVDT_OFF + idx] = (f_acc[idx] - c * vv * mi) / mi;
        out[V_OFF + idx] = vv;
        ke += 0.5f * mi * vv * vv;
    }
    red[t] = ke;
    __syncthreads();
    for (int s = 128; s > 0; s >>= 1) {
        if (t < s) red[t] += red[t + s];
        __syncthreads();
    }
    if (t == 0) {
        float k0 = red[0];
        float e0 = p_eta[0], e1 = p_eta[1], e2 = p_eta[2], e3 = p_eta[3];
        out[PETA_OFF + 0] = 2.f * (k0 - TARGET_KE) - e0 * e1 / QI_F;
        out[PETA_OFF + 1] = e0 * e0 / Q0_F - KT_F - e1 * e2 / QI_F;
        out[PETA_OFF + 2] = e1 * e1 / QI_F - KT_F - e2 * e3 / QI_F;
        out[PETA_OFF + 3] = e2 * e2 / QI_F - KT_F;
    }
}

// ---------------------------------------------------------------- launch
extern "C" void kernel_launch(void* const* d_in, const int* in_sizes, int n_in,
                              void* d_out, int out_size, void* d_ws, size_t ws_size,
                              hipStream_t stream)
{
    const float* v     = (const float*)d_in[0];
    const float* q     = (const float*)d_in[1];
    const float* p_eta = (const float*)d_in[2];
    const float* mass  = (const float*)d_in[3];
    const float* embed = (const float*)d_in[4];
    const float* W1    = (const float*)d_in[5];
    const float* b1    = (const float*)d_in[6];
    const float* W2    = (const float*)d_in[7];
    const float* b2    = (const float*)d_in[8];
    const float* W3    = (const float*)d_in[9];
    const float* wout  = (const float*)d_in[10];
    const int*   z     = (const int*)d_in[11];
    float* out = (float*)d_out;

    float* h     = (float*)d_ws;
    float* W2T   = h + N_ATOMS * FD;
    float* W3T   = W2T + FD * FD;
    float* m     = W3T + FD * FD;
    float* mbar  = m + N_ATOMS * FD;
    float* f_acc = mbar + N_ATOMS * FD;
    float* pair_d  = f_acc + 3 * N_ATOMS;
    float* pair_dx = pair_d + N_ATOMS * MAXN;
    float* pair_dy = pair_dx + N_ATOMS * MAXN;
    float* pair_dz = pair_dy + N_ATOMS * MAXN;
    int* pair_i = (int*)(pair_dz + N_ATOMS * MAXN);
    int* pair_j = pair_i + N_ATOMS * MAXN;
    int* npairs_ctr = pair_j + N_ATOMS * MAXN;

    hipMemsetAsync(npairs_ctr, 0, sizeof(int), stream);

    prep_kernel<<<N_ATOMS, 256, 0, stream>>>(q, z, embed, W2, W3, h, W2T, W3T,
                                             pair_i, pair_j, pair_d,
                                             pair_dx, pair_dy, pair_dz,
                                             npairs_ctr, m, f_acc);
    fwd_kernel<<<FTILES, 256, 0, stream>>>(W1, b1, W2, b2, h, pair_i,
                                           pair_j, pair_d, npairs_ctr, m);
    mbar_kernel<<<N_ATOMS, 128, 0, stream>>>(m, W3, W3T, wout, mbar);
    bwd_kernel<<<BTILES, 256, 0, stream>>>(W1, b1, W2T, h, mbar, pair_i,
                                           pair_j, pair_d, pair_dx, pair_dy,
                                           pair_dz, npairs_ctr, f_acc);
    fin_kernel<<<1, 256, 0, stream>>>(v, mass, p_eta, f_acc, out);
}

// Round 16
// 164.238 us; speedup vs baseline: 2.0655x; 1.0361x over previous
//
#include <hip/hip_runtime.h>
#include <math.h>

// Problem constants (match reference)
#define N_ATOMS 768
#define FD 128          // feature width
#define NRBF 32
#define MAXN 64         // per-atom neighbor cap (mean ~26)
#define PPF 32          // fwd: pairs per block (4 pairs x 4 cols per thread)
#define PPBW 16         // bwd: pairs per block (2 pairs x 4 cols per thread)
#define FTILES (N_ATOMS * MAXN / PPF)     // 1536
#define BTILES (N_ATOMS * MAXN / PPBW)    // 3072
#define AST 132         // padded LDS stride for [*][128] tiles (16B-aligned)
#define RST 36          // padded LDS stride for [*][32] rbf tiles

constexpr float  CUT2   = 25.0f;
constexpr float  GAMMA_ = 40.96f;            // 1/(5/32)^2
constexpr float  CSTEP  = 5.0f / 31.0f;      // linspace(0,5,32) step
constexpr double KB_D   = 8.617330337217213e-05;
constexpr double KT_D   = 300.0 * KB_D;
constexpr float  KT_F   = (float)KT_D;
constexpr float  TARGET_KE = (float)(0.5 * 2304.0 * KT_D);
constexpr float  Q0_F   = (float)(2.0 * 2304.0 * KT_D * 400.0);  // Q[0]
constexpr float  QI_F   = (float)(2.0 * KT_D * 400.0);           // Q[1..3]

#define DVDT_OFF 0
#define V_OFF    (3 * N_ATOMS)
#define PETA_OFF (6 * N_ATOMS)

// Hard-won rules (15 rounds of counters):
// 1. NO __launch_bounds__ min-wave hints on GEMM kernels — compiler squeezes
//    VGPRs below demand -> scratch spills -> 100s-of-MB symmetric FETCH/WRITE,
//    dur ~ spill/2.5 TB/s (R3/R5/R6/R7/R9/R11).
// 2. Reduce register demand STRUCTURALLY — phase-split through LDS so heavy
//    phases don't overlap (R12 bwd: 220->80->48 VGPR; R16 applies to fwd).
// 3. Tile economics differ per kernel: fwd wants PPF=32 (W2 stream amortized),
//    bwd wants PPBW=16 (grid fill; lighter inner loop) (R12/R13).
// 4. NEVER put __threadfence / completion counters on the hot grid — device
//    fence ~ L2 flush per block: R14 bwd 44.6 -> 225 us (also explains R8).

// ---------------------------------------------------------------- prep
__global__ __launch_bounds__(256) void prep_kernel(
    const float* __restrict__ q, const int* __restrict__ z,
    const float* __restrict__ embed, const float* __restrict__ W2,
    const float* __restrict__ W3,
    float* __restrict__ h, float* __restrict__ W2T, float* __restrict__ W3T,
    int* __restrict__ pair_i, int* __restrict__ pair_j,
    float* __restrict__ pair_d, float* __restrict__ pair_dx,
    float* __restrict__ pair_dy, float* __restrict__ pair_dz,
    int* __restrict__ npairs_ctr,
    float* __restrict__ m, float* __restrict__ f_acc)
{
    __shared__ int   nj[MAXN];
    __shared__ float nd[MAXN], ndx[MAXN], ndy[MAXN], ndz[MAXN];
    __shared__ int cnt_s, base_s;
    int i = blockIdx.x, t = threadIdx.x;
    if (t == 0) cnt_s = 0;
    __syncthreads();
    float qx = q[i*3], qy = q[i*3+1], qz = q[i*3+2];
    for (int j = t; j < N_ATOMS; j += 256) {
        if (j == i) continue;
        float dx = qx - q[j*3], dy = qy - q[j*3+1], dz = qz - q[j*3+2];
        float d2 = dx*dx + dy*dy + dz*dz;
        if (d2 < CUT2) {
            int p = atomicAdd(&cnt_s, 1);
            if (p < MAXN) { nj[p] = j; nd[p] = sqrtf(d2);
                            ndx[p] = dx; ndy[p] = dy; ndz[p] = dz; }
        }
    }
    int g = i * 256 + t;                         // 196608 global ids
    if (g < N_ATOMS * FD) { h[g] = embed[z[g >> 7] * FD + (g & 127)]; m[g] = 0.f; }
    int g2 = g - N_ATOMS * FD;
    if (g2 >= 0 && g2 < FD * FD) {
        int r = g2 >> 7, c = g2 & 127;
        W2T[c * FD + r] = W2[g2];
        W3T[c * FD + r] = W3[g2];
    }
    if (g < 3 * N_ATOMS) f_acc[g] = 0.f;
    __syncthreads();
    if (t == 0) base_s = atomicAdd(npairs_ctr, min(cnt_s, MAXN));
    __syncthreads();
    int cnt = min(cnt_s, MAXN), base = base_s;
    if (t < cnt) {
        pair_i[base+t] = i;      pair_j[base+t] = nj[t];
        pair_d[base+t] = nd[t];  pair_dx[base+t] = ndx[t];
        pair_dy[base+t] = ndy[t]; pair_dz[base+t] = ndz[t];
    }
}

// ---------------------------------------------------------------- fwd (PPF=32)
// R16 register-diet restructure: three phases through LDS so heavy register
// sets never co-live. Phase A: GEMM-1 -> a1_s. Phase B: GEMM-2 -> filt_s
// (acc dies at phase end). Phase C: thread=(col, 16-pair half), run-segmented
// m[i,c] += (filt+b2)*h[j,c] — one scalar atomic per (col,run).
__global__ __launch_bounds__(256) void fwd_kernel(
    const float* __restrict__ W1, const float* __restrict__ b1,
    const float* __restrict__ W2, const float* __restrict__ b2,
    const float* __restrict__ h,
    const int* __restrict__ pair_i, const int* __restrict__ pair_j,
    const float* __restrict__ pair_d, const int* __restrict__ npairs_ctr,
    float* __restrict__ m)
{
    __shared__ float rbf_s[PPF * RST];    //  4608 B
    __shared__ float a1_s[PPF * AST];     // 16896 B
    __shared__ float filt_s[PPF * AST];   // 16896 B
    __shared__ int   pis[PPF], pjs[PPF];  //   256 B  (total ~38.7 KB -> 4/CU)
    int t = threadIdx.x;
    int base = blockIdx.x * PPF;
    int np = npairs_ctr[0];
    if (base >= np) return;

    if (t < PPF) {
        int p = base + t; bool ok = p < np;
        pis[t] = ok ? pair_i[p] : 0;
        pjs[t] = ok ? pair_j[p] : 0;
    }
    for (int idx = t; idx < PPF * NRBF; idx += 256) {
        int p = idx >> 5, k = idx & 31;
        int gp = base + p;
        float d = (gp < np) ? pair_d[gp] : 1.0f;
        float u = d - CSTEP * (float)k;
        rbf_s[p * RST + k] = __expf(-GAMMA_ * u * u);
    }
    __syncthreads();

    // Phase A: a1[p][c] = relu(b1[c] + rbf[p]@W1[:,c]); thread = (c, 16-pair half)
    {
        int c = t & 127, ph = t >> 7;
        float w1c[NRBF];
#pragma unroll
        for (int k = 0; k < NRBF; k++) w1c[k] = W1[k * FD + c];
        float b1c = b1[c];
        for (int p = ph * 16; p < ph * 16 + 16; p++) {
            float u = b1c;
#pragma unroll
            for (int k4 = 0; k4 < NRBF / 4; k4++) {
                float4 r = *(const float4*)(rbf_s + p * RST + k4 * 4);
                u += r.x*w1c[k4*4] + r.y*w1c[k4*4+1] + r.z*w1c[k4*4+2] + r.w*w1c[k4*4+3];
            }
            a1_s[p * AST + c] = fmaxf(u, 0.f);
        }
    }
    __syncthreads();

    // Phase B: filt[p][c4..] = a1[p] @ W2[:,c4..]  (raw; b2 added in phase C)
    {
        int st = t >> 5, cg = t & 31, c4 = 4 * cg;
        float acc[4][4];
#pragma unroll
        for (int e = 0; e < 4; e++) { acc[e][0]=0; acc[e][1]=0; acc[e][2]=0; acc[e][3]=0; }
        for (int k = 0; k < FD; k += 4) {
            float4 w0 = *(const float4*)(W2 + (k+0) * FD + c4);
            float4 w1v= *(const float4*)(W2 + (k+1) * FD + c4);
            float4 w2v= *(const float4*)(W2 + (k+2) * FD + c4);
            float4 w3v= *(const float4*)(W2 + (k+3) * FD + c4);
#pragma unroll
            for (int e = 0; e < 4; e++) {
                float4 a = *(const float4*)(a1_s + (st*4+e) * AST + k);
                acc[e][0] += a.x*w0.x + a.y*w1v.x + a.z*w2v.x + a.w*w3v.x;
                acc[e][1] += a.x*w0.y + a.y*w1v.y + a.z*w2v.y + a.w*w3v.y;
                acc[e][2] += a.x*w0.z + a.y*w1v.z + a.z*w2v.z + a.w*w3v.z;
                acc[e][3] += a.x*w0.w + a.y*w1v.w + a.z*w2v.w + a.w*w3v.w;
            }
        }
#pragma unroll
        for (int e = 0; e < 4; e++) {
            float4 fv; fv.x = acc[e][0]; fv.y = acc[e][1];
            fv.z = acc[e][2]; fv.w = acc[e][3];
            *(float4*)(filt_s + (st*4+e) * AST + c4) = fv;
        }
    }
    __syncthreads();

    // Phase C: m[i,c] += (filt[p][c]+b2[c]) * h[j_p][c]; thread = (c, half)
    {
        int c = t & 127, ph = t >> 7;
        float b2c = b2[c];
        float r = 0.f;
        int p0 = ph * 16;
        int cur_i = pis[p0];
        for (int p = p0; p < p0 + 16; p++) {
            int ip = pis[p];
            if (ip != cur_i) {
                atomicAdd(m + cur_i * FD + c, r);
                r = 0.f; cur_i = ip;
            }
            if (base + p < np)
                r += (filt_s[p * AST + c] + b2c) * h[pjs[p] * FD + c];
        }
        atomicAdd(m + cur_i * FD + c, r);
    }
}

// ---------------------------------------------------------------- mbar (per atom)
__global__ __launch_bounds__(128) void mbar_kernel(
    const float* __restrict__ m, const float* __restrict__ W3,
    const float* __restrict__ W3T, const float* __restrict__ w_out,
    float* __restrict__ mbar)
{
    __shared__ float ms[FD];
    __shared__ float gb[FD];
    int i = blockIdx.x, t = threadIdx.x;
    ms[t] = m[i * FD + t];
    __syncthreads();
    float g = 0.f;
#pragma unroll 8
    for (int f = 0; f < FD; f++) g += ms[f] * W3[f * FD + t];
    gb[t] = (g > 0.f) ? w_out[t] : 0.f;
    __syncthreads();
    float mb = 0.f;
#pragma unroll 8
    for (int c = 0; c < FD; c++) mb += gb[c] * W3T[c * FD + t];
    mbar[i * FD + t] = mb;
}

// ---------------------------------------------------------------- bwd (PPBW=16)
// R12 register-diet structure (gef phase in LDS), R13 tile size. No fences.
__global__ __launch_bounds__(256) void bwd_kernel(
    const float* __restrict__ W1, const float* __restrict__ b1,
    const float* __restrict__ W2T, const float* __restrict__ h,
    const float* __restrict__ mbar,
    const int* __restrict__ pair_i, const int* __restrict__ pair_j,
    const float* __restrict__ pair_d, const float* __restrict__ pair_dx,
    const float* __restrict__ pair_dy, const float* __restrict__ pair_dz,
    const int* __restrict__ npairs_ctr, float* __restrict__ f_acc)
{
    __shared__ float rbf_s[PPBW * RST];    //  2304 B
    __shared__ float crbf_s[PPBW * RST];   //  2304 B
    __shared__ float ts[PPBW * AST];       //  8448 B
    __shared__ float gef[PPBW * AST];      //  8448 B
    __shared__ int   pis[PPBW], pjs[PPBW];
    int t = threadIdx.x;
    int base = blockIdx.x * PPBW;
    int np = npairs_ctr[0];
    if (base >= np) return;

    if (t < PPBW) {
        int p = base + t; bool ok = p < np;
        pis[t] = ok ? pair_i[p] : 0;
        pjs[t] = ok ? pair_j[p] : 0;
    }
    for (int idx = t; idx < PPBW * NRBF; idx += 256) {
        int p = idx >> 5, k = idx & 31;
        int gp = base + p;
        float d = (gp < np) ? pair_d[gp] : 1.0f;
        float u = d - CSTEP * (float)k;
        float r = __expf(-GAMMA_ * u * u);
        rbf_s[p * RST + k]  = r;
        crbf_s[p * RST + k] = -2.f * GAMMA_ * u * r;
    }
    __syncthreads();                       // pis/pjs + rbf/crbf ready

    // ts tile: ts[p][c] = mbar_i[c] * h[j_p][c]
    for (int idx = t; idx < PPBW * 32; idx += 256) {
        int p = idx >> 5, c4g = (idx & 31) * 4;
        float4 mb4 = *(const float4*)(mbar + pis[p] * FD + c4g);
        float4 hj4 = *(const float4*)(h + pjs[p] * FD + c4g);
        float4 tv; tv.x = mb4.x*hj4.x; tv.y = mb4.y*hj4.y;
        tv.z = mb4.z*hj4.z; tv.w = mb4.w*hj4.w;
        *(float4*)(ts + p * AST + c4g) = tv;
    }
    // gef phase: thread = (c, 8-pair half); w1c regs die at phase end
    {
        int c = t & 127, ph = t >> 7;
        float w1c[NRBF];
#pragma unroll
        for (int k = 0; k < NRBF; k++) w1c[k] = W1[k * FD + c];
        float b1c = b1[c];
        for (int p = ph * 8; p < ph * 8 + 8; p++) {
            float u1 = b1c, ef = 0.f;
#pragma unroll
            for (int k4 = 0; k4 < NRBF / 4; k4++) {
                float4 r = *(const float4*)(rbf_s  + p * RST + k4 * 4);
                float4 cd= *(const float4*)(crbf_s + p * RST + k4 * 4);
                u1 += r.x*w1c[k4*4] + r.y*w1c[k4*4+1] + r.z*w1c[k4*4+2] + r.w*w1c[k4*4+3];
                ef += cd.x*w1c[k4*4] + cd.y*w1c[k4*4+1] + cd.z*w1c[k4*4+2] + cd.w*w1c[k4*4+3];
            }
            gef[p * AST + c] = (u1 > 0.f) ? ef : 0.f;
        }
    }
    __syncthreads();

    // GEMM: du1[p][c4..] = ts[p] @ W2T[:,c4..]; fold gef immediately.
    int st = t >> 5, cg = t & 31, c4 = 4 * cg;
    float acc[2][4];
#pragma unroll
    for (int e = 0; e < 2; e++) { acc[e][0]=0; acc[e][1]=0; acc[e][2]=0; acc[e][3]=0; }
    for (int k = 0; k < FD; k += 4) {
        float4 w0 = *(const float4*)(W2T + (k+0) * FD + c4);
        float4 w1v= *(const float4*)(W2T + (k+1) * FD + c4);
        float4 w2v= *(const float4*)(W2T + (k+2) * FD + c4);
        float4 w3v= *(const float4*)(W2T + (k+3) * FD + c4);
#pragma unroll
        for (int e = 0; e < 2; e++) {
            float4 a = *(const float4*)(ts + (st*2+e) * AST + k);
            acc[e][0] += a.x*w0.x + a.y*w1v.x + a.z*w2v.x + a.w*w3v.x;
            acc[e][1] += a.x*w0.y + a.y*w1v.y + a.z*w2v.y + a.w*w3v.y;
            acc[e][2] += a.x*w0.z + a.y*w1v.z + a.z*w2v.z + a.w*w3v.z;
            acc[e][3] += a.x*w0.w + a.y*w1v.w + a.z*w2v.w + a.w*w3v.w;
        }
    }
#pragma unroll
    for (int e = 0; e < 2; e++) {
        float4 g4 = *(const float4*)(gef + (st*2+e) * AST + c4);
        float s = acc[e][0]*g4.x + acc[e][1]*g4.y + acc[e][2]*g4.z + acc[e][3]*g4.w;
        s += __shfl_xor(s, 1, 64);
        s += __shfl_xor(s, 2, 64);
        s += __shfl_xor(s, 4, 64);
        s += __shfl_xor(s, 8, 64);
        s += __shfl_xor(s, 16, 64);
        int gp = base + st * 2 + e;
        if (cg == e && gp < np) {
            int ii = pis[st * 2 + e], jj = pjs[st * 2 + e];
            float coef = s / pair_d[gp];
            float fx = coef * pair_dx[gp];
            float fy = coef * pair_dy[gp];
            float fz = coef * pair_dz[gp];
            atomicAdd(f_acc + ii*3 + 0, -fx);
            atomicAdd(f_acc + ii*3 + 1, -fy);
            atomicAdd(f_acc + ii*3 + 2, -fz);
            atomicAdd(f_acc + jj*3 + 0, fx);
            atomicAdd(f_acc + jj*3 + 1, fy);
            atomicAdd(f_acc + jj*3 + 2, fz);
        }
    }
}

// ---------------------------------------------------------------- finalize
__global__ __launch_bounds__(256) void fin_kernel(
    const float* __restrict__ v, const float* __restrict__ mass,
    const float* __restrict__ p_eta, const float* __restrict__ f_acc,
    float* __restrict__ out)
{
    __shared__ float red[256];
    int t = threadIdx.x;
    float ke = 0.f;
    float c = p_eta[0] / Q0_F;
    for (int idx = t; idx < 3 * N_ATOMS; idx += 256) {
        int a = idx / 3;
        float vv = v[idx], mi = mass[a];
        out[DVDT_OFF + idx] = (f_acc[idx] - c * vv * mi) / mi;
        out[V_OFF + idx] = vv;
        ke += 0.5f * mi * vv * vv;
    }
    red[t] = ke;
    __syncthreads();
    for (int s = 128; s > 0; s >>= 1) {
        if (t < s) red[t] += red[t + s];
        __syncthreads();
    }
    if (t == 0) {
        float k0 = red[0];
        float e0 = p_eta[0], e1 = p_eta[1], e2 = p_eta[2], e3 = p_eta[3];
        out[PETA_OFF + 0] = 2.f * (k0 - TARGET_KE) - e0 * e1 / QI_F;
        out[PETA_OFF + 1] = e0 * e0 / Q0_F - KT_F - e1 * e2 / QI_F;
        out[PETA_OFF + 2] = e1 * e1 / QI_F - KT_F - e2 * e3 / QI_F;
        out[PETA_OFF + 3] = e2 * e2 / QI_F - KT_F;
    }
}

// ---------------------------------------------------------------- launch
extern "C" void kernel_launch(void* const* d_in, const int* in_sizes, int n_in,
                              void* d_out, int out_size, void* d_ws, size_t ws_size,
                              hipStream_t stream)
{
    const float* v     = (const float*)d_in[0];
    const float* q     = (const float*)d_in[1];
    const float* p_eta = (const float*)d_in[2];
    const float* mass  = (const float*)d_in[3];
    const float* embed = (const float*)d_in[4];
    const float* W1    = (const float*)d_in[5];
    const float* b1    = (const float*)d_in[6];
    const float* W2    = (const float*)d_in[7];
    const float* b2    = (const float*)d_in[8];
    const float* W3    = (const float*)d_in[9];
    const float* wout  = (const float*)d_in[10];
    const int*   z     = (const int*)d_in[11];
    float* out = (float*)d_out;

    float* h     = (float*)d_ws;
    float* W2T   = h + N_ATOMS * FD;
    float* W3T   = W2T + FD * FD;
    float* m     = W3T + FD * FD;
    float* mbar  = m + N_ATOMS * FD;
    float* f_acc = mbar + N_ATOMS * FD;
    float* pair_d  = f_acc + 3 * N_ATOMS;
    float* pair_dx = pair_d + N_ATOMS * MAXN;
    float* pair_dy = pair_dx + N_ATOMS * MAXN;
    float* pair_dz = pair_dy + N_ATOMS * MAXN;
    int* pair_i = (int*)(pair_dz + N_ATOMS * MAXN);
    int* pair_j = pair_i + N_ATOMS * MAXN;
    int* npairs_ctr = pair_j + N_ATOMS * MAXN;

    hipMemsetAsync(npairs_ctr, 0, sizeof(int), stream);

    prep_kernel<<<N_ATOMS, 256, 0, stream>>>(q, z, embed, W2, W3, h, W2T, W3T,
                                             pair_i, pair_j, pair_d,
                                             pair_dx, pair_dy, pair_dz,
                                             npairs_ctr, m, f_acc);
    fwd_kernel<<<FTILES, 256, 0, stream>>>(W1, b1, W2, b2, h, pair_i,
                                           pair_j, pair_d, npairs_ctr, m);
    mbar_kernel<<<N_ATOMS, 128, 0, stream>>>(m, W3, W3T, wout, mbar);
    bwd_kernel<<<BTILES, 256, 0, stream>>>(W1, b1, W2T, h, mbar, pair_i,
                                           pair_j, pair_d, pair_dx, pair_dy,
                                           pair_dz, npairs_ctr, f_acc);
    fin_kernel<<<1, 256, 0, stream>>>(v, mass, p_eta, f_acc, out);
}

// Round 17
// 162.798 us; speedup vs baseline: 2.0837x; 1.0088x over previous
//
#include <hip/hip_runtime.h>
#include <math.h>

// Problem constants (match reference)
#define N_ATOMS 768
#define FD 128          // feature width
#define NRBF 32
#define MAXN 64         // per-atom neighbor cap (mean ~26)
#define PPF 32          // fwd: pairs per block (4 pairs x 4 cols per thread)
#define PPBW 16         // bwd: pairs per block (2 pairs x 4 cols per thread)
#define FTILES (N_ATOMS * MAXN / PPF)     // 1536
#define BTILES (N_ATOMS * MAXN / PPBW)    // 3072
#define AST 132         // padded LDS stride for [*][128] tiles (16B-aligned)
#define RST 36          // padded LDS stride for [*][32] rbf tiles

constexpr float  CUT2   = 25.0f;
constexpr float  GAMMA_ = 40.96f;            // 1/(5/32)^2
constexpr float  CSTEP  = 5.0f / 31.0f;      // linspace(0,5,32) step
constexpr double KB_D   = 8.617330337217213e-05;
constexpr double KT_D   = 300.0 * KB_D;
constexpr float  KT_F   = (float)KT_D;
constexpr float  TARGET_KE = (float)(0.5 * 2304.0 * KT_D);
constexpr float  Q0_F   = (float)(2.0 * 2304.0 * KT_D * 400.0);  // Q[0]
constexpr float  QI_F   = (float)(2.0 * KT_D * 400.0);           // Q[1..3]

#define DVDT_OFF 0
#define V_OFF    (3 * N_ATOMS)
#define PETA_OFF (6 * N_ATOMS)

// Hard-won rules (16 rounds of counters):
// 1. NO __launch_bounds__ min-wave hints on GEMM kernels — compiler squeezes
//    VGPRs below demand -> scratch spills -> 100s-of-MB symmetric FETCH/WRITE,
//    dur ~ spill/2.5 TB/s (R3/R5/R6/R7/R9/R11).
// 2. Reduce register demand STRUCTURALLY — phase-split through LDS so heavy
//    phases don't overlap (R12 bwd 220->48 VGPR; R16 fwd diet -> 164 us).
// 3. Tile economics differ per kernel: fwd wants PPF=32 (W2 stream amortized),
//    bwd wants PPBW=16 (grid fill; lighter inner loop) (R12/R13).
// 4. NEVER put __threadfence / completion counters on the hot grid — device
//    fence ~ L2 flush per block: R14 bwd 44.6 -> 225 us (also explains R8).
// 5. R17: mbar fused into bwd by REDUNDANT RECOMPUTE per block (dispatch
//    boundary provides the sync; no fences) — kills one dispatch.

// ---------------------------------------------------------------- prep
__global__ __launch_bounds__(256) void prep_kernel(
    const float* __restrict__ q, const int* __restrict__ z,
    const float* __restrict__ embed, const float* __restrict__ W2,
    const float* __restrict__ W3,
    float* __restrict__ h, float* __restrict__ W2T, float* __restrict__ W3T,
    int* __restrict__ pair_i, int* __restrict__ pair_j,
    float* __restrict__ pair_d, float* __restrict__ pair_dx,
    float* __restrict__ pair_dy, float* __restrict__ pair_dz,
    int* __restrict__ npairs_ctr,
    float* __restrict__ m, float* __restrict__ f_acc)
{
    __shared__ int   nj[MAXN];
    __shared__ float nd[MAXN], ndx[MAXN], ndy[MAXN], ndz[MAXN];
    __shared__ int cnt_s, base_s;
    int i = blockIdx.x, t = threadIdx.x;
    if (t == 0) cnt_s = 0;
    __syncthreads();
    float qx = q[i*3], qy = q[i*3+1], qz = q[i*3+2];
    for (int j = t; j < N_ATOMS; j += 256) {
        if (j == i) continue;
        float dx = qx - q[j*3], dy = qy - q[j*3+1], dz = qz - q[j*3+2];
        float d2 = dx*dx + dy*dy + dz*dz;
        if (d2 < CUT2) {
            int p = atomicAdd(&cnt_s, 1);
            if (p < MAXN) { nj[p] = j; nd[p] = sqrtf(d2);
                            ndx[p] = dx; ndy[p] = dy; ndz[p] = dz; }
        }
    }
    int g = i * 256 + t;                         // 196608 global ids
    if (g < N_ATOMS * FD) { h[g] = embed[z[g >> 7] * FD + (g & 127)]; m[g] = 0.f; }
    int g2 = g - N_ATOMS * FD;
    if (g2 >= 0 && g2 < FD * FD) {
        int r = g2 >> 7, c = g2 & 127;
        W2T[c * FD + r] = W2[g2];
        W3T[c * FD + r] = W3[g2];
    }
    if (g < 3 * N_ATOMS) f_acc[g] = 0.f;
    __syncthreads();
    if (t == 0) base_s = atomicAdd(npairs_ctr, min(cnt_s, MAXN));
    __syncthreads();
    int cnt = min(cnt_s, MAXN), base = base_s;
    if (t < cnt) {
        pair_i[base+t] = i;      pair_j[base+t] = nj[t];
        pair_d[base+t] = nd[t];  pair_dx[base+t] = ndx[t];
        pair_dy[base+t] = ndy[t]; pair_dz[base+t] = ndz[t];
    }
}

// ---------------------------------------------------------------- fwd (PPF=32)
// R16 three-phase register-diet structure (best known).
__global__ __launch_bounds__(256) void fwd_kernel(
    const float* __restrict__ W1, const float* __restrict__ b1,
    const float* __restrict__ W2, const float* __restrict__ b2,
    const float* __restrict__ h,
    const int* __restrict__ pair_i, const int* __restrict__ pair_j,
    const float* __restrict__ pair_d, const int* __restrict__ npairs_ctr,
    float* __restrict__ m)
{
    __shared__ float rbf_s[PPF * RST];    //  4608 B
    __shared__ float a1_s[PPF * AST];     // 16896 B
    __shared__ float filt_s[PPF * AST];   // 16896 B
    __shared__ int   pis[PPF], pjs[PPF];  //   256 B  (total ~38.7 KB)
    int t = threadIdx.x;
    int base = blockIdx.x * PPF;
    int np = npairs_ctr[0];
    if (base >= np) return;

    if (t < PPF) {
        int p = base + t; bool ok = p < np;
        pis[t] = ok ? pair_i[p] : 0;
        pjs[t] = ok ? pair_j[p] : 0;
    }
    for (int idx = t; idx < PPF * NRBF; idx += 256) {
        int p = idx >> 5, k = idx & 31;
        int gp = base + p;
        float d = (gp < np) ? pair_d[gp] : 1.0f;
        float u = d - CSTEP * (float)k;
        rbf_s[p * RST + k] = __expf(-GAMMA_ * u * u);
    }
    __syncthreads();

    // Phase A: a1[p][c] = relu(b1[c] + rbf[p]@W1[:,c]); thread = (c, 16-pair half)
    {
        int c = t & 127, ph = t >> 7;
        float w1c[NRBF];
#pragma unroll
        for (int k = 0; k < NRBF; k++) w1c[k] = W1[k * FD + c];
        float b1c = b1[c];
        for (int p = ph * 16; p < ph * 16 + 16; p++) {
            float u = b1c;
#pragma unroll
            for (int k4 = 0; k4 < NRBF / 4; k4++) {
                float4 r = *(const float4*)(rbf_s + p * RST + k4 * 4);
                u += r.x*w1c[k4*4] + r.y*w1c[k4*4+1] + r.z*w1c[k4*4+2] + r.w*w1c[k4*4+3];
            }
            a1_s[p * AST + c] = fmaxf(u, 0.f);
        }
    }
    __syncthreads();

    // Phase B: filt[p][c4..] = a1[p] @ W2[:,c4..]  (raw; b2 added in phase C)
    {
        int st = t >> 5, cg = t & 31, c4 = 4 * cg;
        float acc[4][4];
#pragma unroll
        for (int e = 0; e < 4; e++) { acc[e][0]=0; acc[e][1]=0; acc[e][2]=0; acc[e][3]=0; }
        for (int k = 0; k < FD; k += 4) {
            float4 w0 = *(const float4*)(W2 + (k+0) * FD + c4);
            float4 w1v= *(const float4*)(W2 + (k+1) * FD + c4);
            float4 w2v= *(const float4*)(W2 + (k+2) * FD + c4);
            float4 w3v= *(const float4*)(W2 + (k+3) * FD + c4);
#pragma unroll
            for (int e = 0; e < 4; e++) {
                float4 a = *(const float4*)(a1_s + (st*4+e) * AST + k);
                acc[e][0] += a.x*w0.x + a.y*w1v.x + a.z*w2v.x + a.w*w3v.x;
                acc[e][1] += a.x*w0.y + a.y*w1v.y + a.z*w2v.y + a.w*w3v.y;
                acc[e][2] += a.x*w0.z + a.y*w1v.z + a.z*w2v.z + a.w*w3v.z;
                acc[e][3] += a.x*w0.w + a.y*w1v.w + a.z*w2v.w + a.w*w3v.w;
            }
        }
#pragma unroll
        for (int e = 0; e < 4; e++) {
            float4 fv; fv.x = acc[e][0]; fv.y = acc[e][1];
            fv.z = acc[e][2]; fv.w = acc[e][3];
            *(float4*)(filt_s + (st*4+e) * AST + c4) = fv;
        }
    }
    __syncthreads();

    // Phase C: m[i,c] += (filt[p][c]+b2[c]) * h[j_p][c]; thread = (c, half)
    {
        int c = t & 127, ph = t >> 7;
        float b2c = b2[c];
        float r = 0.f;
        int p0 = ph * 16;
        int cur_i = pis[p0];
        for (int p = p0; p < p0 + 16; p++) {
            int ip = pis[p];
            if (ip != cur_i) {
                atomicAdd(m + cur_i * FD + c, r);
                r = 0.f; cur_i = ip;
            }
            if (base + p < np)
                r += (filt_s[p * AST + c] + b2c) * h[pjs[p] * FD + c];
        }
        atomicAdd(m + cur_i * FD + c, r);
    }
}

// ---------------------------------------------------------------- bwd (PPBW=16)
// R12/R13 register-diet structure + fused in-block mbar recompute (R17):
// for each distinct atom i in the tile, mbar_i = W3T @ (wout*gate(m_i@W3))
// computed from the completed m (fwd dispatch boundary = sync). No fences.
__global__ __launch_bounds__(256) void bwd_kernel(
    const float* __restrict__ W1, const float* __restrict__ b1,
    const float* __restrict__ W2T, const float* __restrict__ h,
    const float* __restrict__ m, const float* __restrict__ W3,
    const float* __restrict__ W3T, const float* __restrict__ wout,
    const int* __restrict__ pair_i, const int* __restrict__ pair_j,
    const float* __restrict__ pair_d, const float* __restrict__ pair_dx,
    const float* __restrict__ pair_dy, const float* __restrict__ pair_dz,
    const int* __restrict__ npairs_ctr, float* __restrict__ f_acc)
{
    __shared__ float rbf_s[PPBW * RST];    //  2304 B
    __shared__ float crbf_s[PPBW * RST];   //  2304 B
    __shared__ float ts[PPBW * AST];       //  8448 B
    __shared__ float gef[PPBW * AST];      //  8448 B
    __shared__ float mrow[FD], gbrow[FD], mbrow[FD];   // 1536 B
    __shared__ int   pis[PPBW], pjs[PPBW];
    __shared__ int   da_s[PPBW];
    __shared__ int   nda_s;
    int t = threadIdx.x;
    int base = blockIdx.x * PPBW;
    int np = npairs_ctr[0];
    if (base >= np) return;

    if (t < PPBW) {
        int p = base + t; bool ok = p < np;
        pis[t] = ok ? pair_i[p] : 0;
        pjs[t] = ok ? pair_j[p] : 0;
    }
    for (int idx = t; idx < PPBW * NRBF; idx += 256) {
        int p = idx >> 5, k = idx & 31;
        int gp = base + p;
        float d = (gp < np) ? pair_d[gp] : 1.0f;
        float u = d - CSTEP * (float)k;
        float r = __expf(-GAMMA_ * u * u);
        rbf_s[p * RST + k]  = r;
        crbf_s[p * RST + k] = -2.f * GAMMA_ * u * r;
    }
    __syncthreads();                       // pis/pjs + rbf/crbf ready

    // distinct atom list (runs are contiguous; typically 1-3 entries)
    if (t == 0) {
        int n = 0;
#pragma unroll
        for (int p = 0; p < PPBW; p++) {
            int ip = pis[p];
            bool seen = false;
            for (int k = 0; k < n; k++) if (da_s[k] == ip) { seen = true; break; }
            if (!seen) da_s[n++] = ip;
        }
        nda_s = n;
    }
    __syncthreads();
    int nda = nda_s;

    // per-distinct-atom mbar recompute + ts fill
    for (int k = 0; k < nda; k++) {
        int ia = da_s[k];
        if (t < FD) mrow[t] = m[ia * FD + t];
        __syncthreads();
        if (t < FD) {
            float g3 = 0.f;
#pragma unroll 8
            for (int f = 0; f < FD; f++) g3 += mrow[f] * W3[f * FD + t];
            gbrow[t] = (g3 > 0.f) ? wout[t] : 0.f;
        }
        __syncthreads();
        if (t < FD) {
            float mb = 0.f;
#pragma unroll 8
            for (int f = 0; f < FD; f++) mb += gbrow[f] * W3T[f * FD + t];
            mbrow[t] = mb;
        }
        __syncthreads();
        for (int idx = t; idx < PPBW * 32; idx += 256) {
            int p = idx >> 5, c4g = (idx & 31) * 4;
            if (pis[p] == ia) {
                float4 mb4 = *(const float4*)(mbrow + c4g);
                float4 hj4 = *(const float4*)(h + pjs[p] * FD + c4g);
                float4 tv; tv.x = mb4.x*hj4.x; tv.y = mb4.y*hj4.y;
                tv.z = mb4.z*hj4.z; tv.w = mb4.w*hj4.w;
                *(float4*)(ts + p * AST + c4g) = tv;
            }
        }
        __syncthreads();                   // mrow reused next iteration
    }

    // gef phase: thread = (c, 8-pair half); w1c regs die at phase end
    {
        int c = t & 127, ph = t >> 7;
        float w1c[NRBF];
#pragma unroll
        for (int k = 0; k < NRBF; k++) w1c[k] = W1[k * FD + c];
        float b1c = b1[c];
        for (int p = ph * 8; p < ph * 8 + 8; p++) {
            float u1 = b1c, ef = 0.f;
#pragma unroll
            for (int k4 = 0; k4 < NRBF / 4; k4++) {
                float4 r = *(const float4*)(rbf_s  + p * RST + k4 * 4);
                float4 cd= *(const float4*)(crbf_s + p * RST + k4 * 4);
                u1 += r.x*w1c[k4*4] + r.y*w1c[k4*4+1] + r.z*w1c[k4*4+2] + r.w*w1c[k4*4+3];
                ef += cd.x*w1c[k4*4] + cd.y*w1c[k4*4+1] + cd.z*w1c[k4*4+2] + cd.w*w1c[k4*4+3];
            }
            gef[p * AST + c] = (u1 > 0.f) ? ef : 0.f;
        }
    }
    __syncthreads();

    // GEMM: du1[p][c4..] = ts[p] @ W2T[:,c4..]; fold gef immediately.
    int st = t >> 5, cg = t & 31, c4 = 4 * cg;
    float acc[2][4];
#pragma unroll
    for (int e = 0; e < 2; e++) { acc[e][0]=0; acc[e][1]=0; acc[e][2]=0; acc[e][3]=0; }
    for (int k = 0; k < FD; k += 4) {
        float4 w0 = *(const float4*)(W2T + (k+0) * FD + c4);
        float4 w1v= *(const float4*)(W2T + (k+1) * FD + c4);
        float4 w2v= *(const float4*)(W2T + (k+2) * FD + c4);
        float4 w3v= *(const float4*)(W2T + (k+3) * FD + c4);
#pragma unroll
        for (int e = 0; e < 2; e++) {
            float4 a = *(const float4*)(ts + (st*2+e) * AST + k);
            acc[e][0] += a.x*w0.x + a.y*w1v.x + a.z*w2v.x + a.w*w3v.x;
            acc[e][1] += a.x*w0.y + a.y*w1v.y + a.z*w2v.y + a.w*w3v.y;
            acc[e][2] += a.x*w0.z + a.y*w1v.z + a.z*w2v.z + a.w*w3v.z;
            acc[e][3] += a.x*w0.w + a.y*w1v.w + a.z*w2v.w + a.w*w3v.w;
        }
    }
#pragma unroll
    for (int e = 0; e < 2; e++) {
        float4 g4 = *(const float4*)(gef + (st*2+e) * AST + c4);
        float s = acc[e][0]*g4.x + acc[e][1]*g4.y + acc[e][2]*g4.z + acc[e][3]*g4.w;
        s += __shfl_xor(s, 1, 64);
        s += __shfl_xor(s, 2, 64);
        s += __shfl_xor(s, 4, 64);
        s += __shfl_xor(s, 8, 64);
        s += __shfl_xor(s, 16, 64);
        int gp = base + st * 2 + e;
        if (cg == e && gp < np) {
            int ii = pis[st * 2 + e], jj = pjs[st * 2 + e];
            float coef = s / pair_d[gp];
            float fx = coef * pair_dx[gp];
            float fy = coef * pair_dy[gp];
            float fz = coef * pair_dz[gp];
            atomicAdd(f_acc + ii*3 + 0, -fx);
            atomicAdd(f_acc + ii*3 + 1, -fy);
            atomicAdd(f_acc + ii*3 + 2, -fz);
            atomicAdd(f_acc + jj*3 + 0, fx);
            atomicAdd(f_acc + jj*3 + 1, fy);
            atomicAdd(f_acc + jj*3 + 2, fz);
        }
    }
}

// ---------------------------------------------------------------- finalize
__global__ __launch_bounds__(256) void fin_kernel(
    const float* __restrict__ v, const float* __restrict__ mass,
    const float* __restrict__ p_eta, const float* __restrict__ f_acc,
    float* __restrict__ out)
{
    __shared__ float red[256];
    int t = threadIdx.x;
    float ke = 0.f;
    float c = p_eta[0] / Q0_F;
    for (int idx = t; idx < 3 * N_ATOMS; idx += 256) {
        int a = idx / 3;
        float vv = v[idx], mi = mass[a];
        out[DVDT_OFF + idx] = (f_acc[idx] - c * vv * mi) / mi;
        out[V_OFF + idx] = vv;
        ke += 0.5f * mi * vv * vv;
    }
    red[t] = ke;
    __syncthreads();
    for (int s = 128; s > 0; s >>= 1) {
        if (t < s) red[t] += red[t + s];
        __syncthreads();
    }
    if (t == 0) {
        float k0 = red[0];
        float e0 = p_eta[0], e1 = p_eta[1], e2 = p_eta[2], e3 = p_eta[3];
        out[PETA_OFF + 0] = 2.f * (k0 - TARGET_KE) - e0 * e1 / QI_F;
        out[PETA_OFF + 1] = e0 * e0 / Q0_F - KT_F - e1 * e2 / QI_F;
        out[PETA_OFF + 2] = e1 * e1 / QI_F - KT_F - e2 * e3 / QI_F;
        out[PETA_OFF + 3] = e2 * e2 / QI_F - KT_F;
    }
}

// ---------------------------------------------------------------- launch
extern "C" void kernel_launch(void* const* d_in, const int* in_sizes, int n_in,
                              void* d_out, int out_size, void* d_ws, size_t ws_size,
                              hipStream_t stream)
{
    const float* v     = (const float*)d_in[0];
    const float* q     = (const float*)d_in[1];
    const float* p_eta = (const float*)d_in[2];
    const float* mass  = (const float*)d_in[3];
    const float* embed = (const float*)d_in[4];
    const float* W1    = (const float*)d_in[5];
    const float* b1    = (const float*)d_in[6];
    const float* W2    = (const float*)d_in[7];
    const float* b2    = (const float*)d_in[8];
    const float* W3    = (const float*)d_in[9];
    const float* wout  = (const float*)d_in[10];
    const int*   z     = (const int*)d_in[11];
    float* out = (float*)d_out;

    float* h     = (float*)d_ws;
    float* W2T   = h + N_ATOMS * FD;
    float* W3T   = W2T + FD * FD;
    float* m     = W3T + FD * FD;
    float* f_acc = m + N_ATOMS * FD;
    float* pair_d  = f_acc + 3 * N_ATOMS;
    float* pair_dx = pair_d + N_ATOMS * MAXN;
    float* pair_dy = pair_dx + N_ATOMS * MAXN;
    float* pair_dz = pair_dy + N_ATOMS * MAXN;
    int* pair_i = (int*)(pair_dz + N_ATOMS * MAXN);
    int* pair_j = pair_i + N_ATOMS * MAXN;
    int* npairs_ctr = pair_j + N_ATOMS * MAXN;

    hipMemsetAsync(npairs_ctr, 0, sizeof(int), stream);

    prep_kernel<<<N_ATOMS, 256, 0, stream>>>(q, z, embed, W2, W3, h, W2T, W3T,
                                             pair_i, pair_j, pair_d,
                                             pair_dx, pair_dy, pair_dz,
                                             npairs_ctr, m, f_acc);
    fwd_kernel<<<FTILES, 256, 0, stream>>>(W1, b1, W2, b2, h, pair_i,
                                           pair_j, pair_d, npairs_ctr, m);
    bwd_kernel<<<BTILES, 256, 0, stream>>>(W1, b1, W2T, h, m, W3, W3T, wout,
                                           pair_i, pair_j, pair_d, pair_dx,
                                           pair_dy, pair_dz, npairs_ctr, f_acc);
    fin_kernel<<<1, 256, 0, stream>>>(v, mass, p_eta, f_acc, out);
}